// Round 5
// baseline (1187.717 us; speedup 1.0000x reference)
//
#include <hip/hip_runtime.h>

// ---------------- problem constants ----------------
#define DDIM 1024          // model dim (K of gemm1, N of gemm2)
#define FDIM 2752          // ffn dim
#define FP   2816          // F padded to 22*128 (zero-padded weights -> no N/K guards)
#define TTOK 8192          // tokens
#define SH_OFF 17408       // routed list capacity (16384 + 8*128 align pad), 128-aligned
#define NA   25600         // SH_OFF + TTOK total assignment rows (h rows)

typedef unsigned short u16;
typedef short bf16x8 __attribute__((ext_vector_type(8)));
typedef float f32x4 __attribute__((ext_vector_type(4)));

__device__ __forceinline__ u16 f2b(float f) {
  unsigned u = __float_as_uint(f);
  u += 0x7fff + ((u >> 16) & 1);   // round-to-nearest-even
  return (u16)(u >> 16);
}

__device__ __forceinline__ float b2f(u16 b) {
  return __uint_as_float(((unsigned)b) << 16);
}

// async global->LDS, 16B per lane. LDS dest is wave-uniform base + lane*16.
__device__ __forceinline__ void async16(const void* g, void* s) {
  __builtin_amdgcn_global_load_lds((const __attribute__((address_space(1))) void*)g,
                                   (__attribute__((address_space(3))) void*)s, 16, 0, 0);
}

// ctrl layout (ints): [0..7] counts, [8..15] cursors, [16..24] off[9], [25] nrb_routed, [26] nrb_total

// ---------------- router: 1 wave per token ----------------
__global__ void router_kernel(const float* __restrict__ x, const float* __restrict__ rw,
                              const float* __restrict__ rb, int* __restrict__ topk_id,
                              float* __restrict__ topk_w, int* __restrict__ ctrl) {
  const int wv = threadIdx.x >> 6, lane = threadIdx.x & 63;
  const int t = blockIdx.x * 4 + wv;
  const float* xr = x + (size_t)t * DDIM;
  float acc[8];
#pragma unroll
  for (int e = 0; e < 8; e++) acc[e] = 0.f;
  for (int d = lane; d < DDIM; d += 64) {
    float xv = xr[d];
    const float4* w4 = (const float4*)(rw + (size_t)d * 8);
    float4 wa = w4[0], wb = w4[1];
    acc[0] += xv * wa.x; acc[1] += xv * wa.y; acc[2] += xv * wa.z; acc[3] += xv * wa.w;
    acc[4] += xv * wb.x; acc[5] += xv * wb.y; acc[6] += xv * wb.z; acc[7] += xv * wb.w;
  }
#pragma unroll
  for (int e = 0; e < 8; e++)
    for (int o = 32; o > 0; o >>= 1) acc[e] += __shfl_xor(acc[e], o, 64);
  if (lane == 0) {
    float l[8];
#pragma unroll
    for (int e = 0; e < 8; e++) l[e] = acc[e] + rb[e];
    int i1 = 0; float b1 = l[0];
#pragma unroll
    for (int e = 1; e < 8; e++) if (l[e] > b1) { b1 = l[e]; i1 = e; }
    int i2 = -1; float b2 = -3.4e38f;
#pragma unroll
    for (int e = 0; e < 8; e++) if (e != i1 && l[e] > b2) { b2 = l[e]; i2 = e; }
    // renormalized top-2 softmax weights: w1 = sigmoid(l1-l2)
    float w1 = 1.f / (1.f + __expf(b2 - b1));
    topk_id[2 * t] = i1; topk_id[2 * t + 1] = i2;
    topk_w[2 * t] = w1;  topk_w[2 * t + 1] = 1.f - w1;
    atomicAdd(&ctrl[i1], 1); atomicAdd(&ctrl[i2], 1);
  }
}

// ---------------- offsets + row-block map (single thread, ~200 iters) ----------------
__global__ void build_kernel(int* __restrict__ ctrl, int2* __restrict__ bmap) {
  if (threadIdx.x != 0 || blockIdx.x != 0) return;
  int o = 0, nrb = 0;
  for (int e = 0; e < 8; e++) {
    ctrl[16 + e] = o;
    int c = ctrl[e];
    int nb = (c + 127) >> 7;
    for (int i = 0; i < nb; i++) bmap[nrb++] = make_int2(o + i * 128, e);
    o += nb * 128;            // 128-aligned segments; o <= 17400 < SH_OFF
  }
  ctrl[25] = nrb;             // routed blocks (<=136)
  ctrl[16 + 8] = SH_OFF;
  for (int i = 0; i < 64; i++) bmap[nrb++] = make_int2(SH_OFF + i * 128, 8);
  ctrl[26] = nrb;             // total (<=200)
}

// ---------------- scatter token ids/weights into per-expert segments ----------------
// also builds the inverse map inv[2t+k] = assignment row of token t's k-th expert
__global__ void fill_kernel(const int* __restrict__ topk_id, const float* __restrict__ topk_w,
                            int* __restrict__ ctrl, int* __restrict__ tok, float* __restrict__ tw,
                            int* __restrict__ inv) {
  int t = blockIdx.x * 256 + threadIdx.x;
  if (t >= TTOK) return;
#pragma unroll
  for (int k = 0; k < 2; k++) {
    int e = topk_id[2 * t + k];
    int pos = atomicAdd(&ctrl[8 + e], 1);
    int idx = ctrl[16 + e] + pos;
    tok[idx] = t; tw[idx] = topk_w[2 * t + k];
    inv[2 * t + k] = idx;
  }
  tok[SH_OFF + t] = t; tw[SH_OFF + t] = 1.0f;
}

// ---------------- x fp32 -> bf16 ----------------
__global__ void cvt_x(const float* __restrict__ x, u16* __restrict__ xb) {
  size_t i = ((size_t)blockIdx.x * 256 + threadIdx.x) * 4;
  float4 v = *(const float4*)(x + i);
  ushort4 o;
  o.x = f2b(v.x); o.y = f2b(v.y); o.z = f2b(v.z); o.w = f2b(v.w);
  *(ushort4*)(xb + i) = o;
}

// ---------------- transpose+cast: out[c][r] = in[r][c] (0 outside R/C) ----------------
__global__ void transpose_cvt(const float* __restrict__ inE, const float* __restrict__ inSh,
                              u16* __restrict__ out, int R, int C, int Cp, int Rp) {
  const float* in = (blockIdx.z < 8) ? inE + (size_t)blockIdx.z * R * C : inSh;
  u16* o = out + (size_t)blockIdx.z * Cp * Rp;
  __shared__ float tile[64 * 65];
  int r0 = blockIdx.x * 64, c0 = blockIdx.y * 64;
#pragma unroll
  for (int i = 0; i < 4; i++) {
    int idx = threadIdx.x + 256 * i;           // 0..1023
    int ri = idx >> 4, c4 = (idx & 15) * 4;    // row 0..63, col 0..60 step 4
    int r = r0 + ri, c = c0 + c4;
    float4 v = make_float4(0.f, 0.f, 0.f, 0.f);
    if (r < R && c < C) v = *(const float4*)(in + (size_t)r * C + c);  // C%4==0 -> full vec
    tile[(c4 + 0) * 65 + ri] = v.x;
    tile[(c4 + 1) * 65 + ri] = v.y;
    tile[(c4 + 2) * 65 + ri] = v.z;
    tile[(c4 + 3) * 65 + ri] = v.w;
  }
  __syncthreads();
#pragma unroll
  for (int i = 0; i < 4; i++) {
    int idx = threadIdx.x + 256 * i;
    int co = idx >> 4, ro4 = (idx & 15) * 4;
    ushort4 s;
    s.x = f2b(tile[co * 65 + ro4 + 0]);
    s.y = f2b(tile[co * 65 + ro4 + 1]);
    s.z = f2b(tile[co * 65 + ro4 + 2]);
    s.w = f2b(tile[co * 65 + ro4 + 3]);
    *(ushort4*)(o + (size_t)(c0 + co) * Rp + (r0 + ro4)) = s;
  }
}

// ==================================================================================
// Register-pipelined GEMMs ("RP"): 512 threads (8 waves 2Mx4N), BM=128, BN=256, BK=32.
// Per iteration t: issue 5 staging DMAs (tile t+3/t+2) and 12 ds_reads of tile t+1's
// fragments into the ALTERNATE register set, then run 32 MFMA on tile t's registers
// with NO wait in between -> LDS service overlaps MFMA issue. One barrier, one
// counted vmcnt(5), one trailing lgkmcnt(0) per K-tile (protects buffer reuse).
// Tile k always occupies buf[k % 3]. Fragment sets named P/Q, loop unrolled 2x.
// XOR chunk swizzle on stage source + read address (both sides), unchanged.
// ==================================================================================

// ---------------- GEMM1: h = silu(Xg)*(Xu), grouped by expert ----------------
// LDS buffer (u16 units): A[0,4096) Bg[4096,12288) Bu[12288,20480); 3 bufs = 122880 B.
__global__ __launch_bounds__(512, 2)
void gemm_gateup(const u16* __restrict__ xb, const u16* __restrict__ wg, const u16* __restrict__ wu,
                 const int* __restrict__ ctrl, const int2* __restrict__ bmap,
                 const int* __restrict__ tok, u16* __restrict__ h) {
  const int xcd = blockIdx.x & 7, i = blockIdx.x >> 3;     // i 0..274
  const int n0 = (i / 25) * 256;                           // 11 values: 0..2560
  const int rblk = xcd * 25 + (i % 25);                    // 0..199
  if (rblk >= ctrl[26]) return;
  int2 be = bmap[rblk];
  const int row0 = be.x, e = be.y;

  extern __shared__ u16 sm[];                              // 3 * 20480 u16

  const int tid = threadIdx.x;
  const int wvb = (tid >> 6) * 512;                        // wave-uniform LDS offset (u16)
  const int ra = tid >> 2;                                 // 0..127
  const int ca = (tid & 3) ^ ((ra >> 1) & 3);              // pre-swizzled source chunk
  const u16* pA  = xb + (size_t)tok[row0 + ra] * DDIM + ca * 8;
  const u16* pG0 = wg + ((size_t)e * FP + n0 + ra) * DDIM + ca * 8;
  const u16* pG1 = pG0 + (size_t)128 * DDIM;
  const u16* pU0 = wu + ((size_t)e * FP + n0 + ra) * DDIM + ca * 8;
  const u16* pU1 = pU0 + (size_t)128 * DDIM;

  const int lane = tid & 63, wv = tid >> 6;
  const int wm = wv >> 2, wn = wv & 3;                     // 2M x 4N waves, 64x64 each
  const int fr = lane & 15, kq = lane >> 4;
  const int kqs8 = (kq ^ ((fr >> 1) & 3)) * 8;             // swizzled read chunk

  f32x4 accg[16], accu[16];
#pragma unroll
  for (int q = 0; q < 16; q++) { accg[q] = (f32x4)(0.0f); accu[q] = (f32x4)(0.0f); }

  // prologue: tile k -> buf[k%3]. Stage AG0,U0 | AG1,U1 | AG2 (13 loads, in order).
  async16(pA,        sm + 0     + wvb);
  async16(pG0,       sm + 4096  + wvb);
  async16(pG1,       sm + 8192  + wvb);
  async16(pU0,       sm + 12288 + wvb);
  async16(pU1,       sm + 16384 + wvb);
  async16(pA  + 32,  sm + 20480 + 0     + wvb);
  async16(pG0 + 32,  sm + 20480 + 4096  + wvb);
  async16(pG1 + 32,  sm + 20480 + 8192  + wvb);
  async16(pU0 + 32,  sm + 20480 + 12288 + wvb);
  async16(pU1 + 32,  sm + 20480 + 16384 + wvb);
  async16(pA  + 64,  sm + 40960 + 0     + wvb);
  async16(pG0 + 64,  sm + 40960 + 4096  + wvb);
  async16(pG1 + 64,  sm + 40960 + 8192  + wvb);
  asm volatile("s_waitcnt vmcnt(5)" ::: "memory");         // AG0,U0,AG1 landed
  __builtin_amdgcn_s_barrier();

  bf16x8 aP[4], gP[4], aQ[4], gQ[4], uT[4];
#pragma unroll
  for (int q = 0; q < 4; q++) {
    aP[q] = *(const bf16x8*)(sm + 0    + (wm * 64 + q * 16 + fr) * 32 + kqs8);
    gP[q] = *(const bf16x8*)(sm + 4096 + (wn * 64 + q * 16 + fr) * 32 + kqs8);
  }
  asm volatile("s_waitcnt lgkmcnt(0)" ::: "memory");       // reads done before iter0 DMA hits buf0
  __builtin_amdgcn_s_barrier();

  int bufC = 0, bufN = 20480, bufS = 40960;                // buf[t%3], buf[(t+1)%3], buf[(t+2)%3]

  auto iter = [&](int T, bf16x8 (&AC)[4], bf16x8 (&GC)[4], bf16x8 (&AN)[4], bf16x8 (&GN)[4]) {
    // stage: AG(T+3) -> bufC (A,G regions; disjoint from U region read below); U(T+2) -> bufS
    if (T + 3 < 32) {
      async16(pA  + (T + 3) * 32, sm + bufC + 0    + wvb);
      async16(pG0 + (T + 3) * 32, sm + bufC + 4096 + wvb);
      async16(pG1 + (T + 3) * 32, sm + bufC + 8192 + wvb);
    }
    if (T + 2 < 32) {
      async16(pU0 + (T + 2) * 32, sm + bufS + 12288 + wvb);
      async16(pU1 + (T + 2) * 32, sm + bufS + 16384 + wvb);
    }
    // reads: U of tile T (bufC, U region), A/G of tile T+1 (bufN)
#pragma unroll
    for (int q = 0; q < 4; q++)
      uT[q] = *(const bf16x8*)(sm + bufC + 12288 + (wn * 64 + q * 16 + fr) * 32 + kqs8);
    if (T + 1 < 32) {
#pragma unroll
      for (int q = 0; q < 4; q++) {
        AN[q] = *(const bf16x8*)(sm + bufN + 0    + (wm * 64 + q * 16 + fr) * 32 + kqs8);
        GN[q] = *(const bf16x8*)(sm + bufN + 4096 + (wn * 64 + q * 16 + fr) * 32 + kqs8);
      }
    }
    __builtin_amdgcn_sched_barrier(0);                     // pin read-issue before MFMAs
    __builtin_amdgcn_s_setprio(1);
#pragma unroll
    for (int mi = 0; mi < 4; mi++)
#pragma unroll
      for (int ni = 0; ni < 4; ni++)
        accg[mi * 4 + ni] = __builtin_amdgcn_mfma_f32_16x16x32_bf16(AC[mi], GC[ni], accg[mi * 4 + ni], 0, 0, 0);
#pragma unroll
    for (int mi = 0; mi < 4; mi++)
#pragma unroll
      for (int ni = 0; ni < 4; ni++)
        accu[mi * 4 + ni] = __builtin_amdgcn_mfma_f32_16x16x32_bf16(AC[mi], uT[ni], accu[mi * 4 + ni], 0, 0, 0);
    __builtin_amdgcn_s_setprio(0);
    asm volatile("s_waitcnt lgkmcnt(0)" ::: "memory");     // all our LDS reads done (buffer reuse safety)
    if (T < 28) asm volatile("s_waitcnt vmcnt(5)" ::: "memory");
    else        asm volatile("s_waitcnt vmcnt(0)" ::: "memory");
    __builtin_amdgcn_s_barrier();
    int tmp = bufC; bufC = bufN; bufN = bufS; bufS = tmp;
  };

  for (int t = 0; t < 32; t += 2) {
    iter(t,     aP, gP, aQ, gQ);
    iter(t + 1, aQ, gQ, aP, gP);
  }

  // epilogue: h = silu(g)*u, bf16. C layout: col=lane&15, row=(lane>>4)*4+reg
#pragma unroll
  for (int mi = 0; mi < 4; mi++)
#pragma unroll
    for (int ni = 0; ni < 4; ni++) {
      f32x4 g = accg[mi * 4 + ni], u = accu[mi * 4 + ni];
#pragma unroll
      for (int r = 0; r < 4; r++) {
        float gv = g[r];
        float hv = (gv * u[r]) / (1.0f + __expf(-gv));
        int row = row0 + wm * 64 + mi * 16 + kq * 4 + r;
        int col = n0 + wn * 64 + ni * 16 + fr;
        h[(size_t)row * FP + col] = f2b(hv);
      }
    }
}

// ---------------- GEMM2a: routed down-projection, plain bf16 stores to hd ----------------
// LDS buffer (u16 units): A[0,4096) B[4096,12288); 3 bufs = 73728 B. NT = 88.
__global__ __launch_bounds__(512, 2)
void gemm_down_r(const u16* __restrict__ h, const u16* __restrict__ wd,
                 const int* __restrict__ ctrl, const int2* __restrict__ bmap,
                 u16* __restrict__ hd) {
  const int xcd = blockIdx.x & 7, i = blockIdx.x >> 3;     // i 0..67
  const int n0 = (i / 17) * 256;                           // 4 values
  const int rblk = xcd * 17 + (i % 17);                    // 0..135
  if (rblk >= ctrl[25]) return;
  int2 be = bmap[rblk];
  const int row0 = be.x, e = be.y;

  extern __shared__ u16 sm[];

  const int tid = threadIdx.x;
  const int wvb = (tid >> 6) * 512;
  const int ra = tid >> 2;
  const int ca = (tid & 3) ^ ((ra >> 1) & 3);
  const u16* pA  = h + (size_t)(row0 + ra) * FP + ca * 8;
  const u16* pB0 = wd + ((size_t)e * DDIM + n0 + ra) * FP + ca * 8;
  const u16* pB1 = pB0 + (size_t)128 * FP;

  const int lane = tid & 63, wv = tid >> 6;
  const int wm = wv >> 2, wn = wv & 3;
  const int fr = lane & 15, kq = lane >> 4;
  const int kqs8 = (kq ^ ((fr >> 1) & 3)) * 8;

  f32x4 acc[16];
#pragma unroll
  for (int q = 0; q < 16; q++) acc[q] = (f32x4)(0.0f);

  // prologue: stage tiles 0,1,2 (9 loads)
  async16(pA,        sm + 0     + wvb);
  async16(pB0,       sm + 4096  + wvb);
  async16(pB1,       sm + 8192  + wvb);
  async16(pA  + 32,  sm + 12288 + 0    + wvb);
  async16(pB0 + 32,  sm + 12288 + 4096 + wvb);
  async16(pB1 + 32,  sm + 12288 + 8192 + wvb);
  async16(pA  + 64,  sm + 24576 + 0    + wvb);
  async16(pB0 + 64,  sm + 24576 + 4096 + wvb);
  async16(pB1 + 64,  sm + 24576 + 8192 + wvb);
  asm volatile("s_waitcnt vmcnt(3)" ::: "memory");         // tiles 0,1 landed
  __builtin_amdgcn_s_barrier();

  bf16x8 aP[4], bP[4], aQ[4], bQ[4];
#pragma unroll
  for (int q = 0; q < 4; q++) {
    aP[q] = *(const bf16x8*)(sm + 0    + (wm * 64 + q * 16 + fr) * 32 + kqs8);
    bP[q] = *(const bf16x8*)(sm + 4096 + (wn * 64 + q * 16 + fr) * 32 + kqs8);
  }
  asm volatile("s_waitcnt lgkmcnt(0)" ::: "memory");
  __builtin_amdgcn_s_barrier();

  int bufC = 0, bufN = 12288, bufS = 24576;

  auto iter = [&](int T, bf16x8 (&AC)[4], bf16x8 (&BC)[4], bf16x8 (&AN)[4], bf16x8 (&BN)[4]) {
    if (T + 3 < 88) {
      async16(pA  + (T + 3) * 32, sm + bufC + 0    + wvb);
      async16(pB0 + (T + 3) * 32, sm + bufC + 4096 + wvb);
      async16(pB1 + (T + 3) * 32, sm + bufC + 8192 + wvb);
    }
    if (T + 1 < 88) {
#pragma unroll
      for (int q = 0; q < 4; q++) {
        AN[q] = *(const bf16x8*)(sm + bufN + 0    + (wm * 64 + q * 16 + fr) * 32 + kqs8);
        BN[q] = *(const bf16x8*)(sm + bufN + 4096 + (wn * 64 + q * 16 + fr) * 32 + kqs8);
      }
    }
    __builtin_amdgcn_sched_barrier(0);
    __builtin_amdgcn_s_setprio(1);
#pragma unroll
    for (int mi = 0; mi < 4; mi++)
#pragma unroll
      for (int ni = 0; ni < 4; ni++)
        acc[mi * 4 + ni] = __builtin_amdgcn_mfma_f32_16x16x32_bf16(AC[mi], BC[ni], acc[mi * 4 + ni], 0, 0, 0);
    __builtin_amdgcn_s_setprio(0);
    asm volatile("s_waitcnt lgkmcnt(0)" ::: "memory");
    if (T < 85) asm volatile("s_waitcnt vmcnt(3)" ::: "memory");
    else        asm volatile("s_waitcnt vmcnt(0)" ::: "memory");
    __builtin_amdgcn_s_barrier();
    int tmp = bufC; bufC = bufN; bufN = bufS; bufS = tmp;
  };

  for (int t = 0; t < 88; t += 2) {
    iter(t,     aP, bP, aQ, bQ);
    iter(t + 1, aQ, bQ, aP, bP);
  }

#pragma unroll
  for (int mi = 0; mi < 4; mi++)
#pragma unroll
    for (int r = 0; r < 4; r++) {
      int row = row0 + wm * 64 + mi * 16 + kq * 4 + r;     // < SH_OFF
      u16* orow = hd + (size_t)row * DDIM;
#pragma unroll
      for (int ni = 0; ni < 4; ni++) {
        int col = n0 + wn * 64 + ni * 16 + fr;
        orow[col] = f2b(acc[mi * 4 + ni][r]);
      }
    }
}

// ---------------- GEMM2b: shared-expert down-projection + fused weighted combine ----------------
__global__ __launch_bounds__(512, 2)
void gemm_down_s(const u16* __restrict__ h, const u16* __restrict__ wd,
                 const u16* __restrict__ hd, const int* __restrict__ inv,
                 const float* __restrict__ tw, float* __restrict__ out) {
  const int xcd = blockIdx.x & 7, i = blockIdx.x >> 3;     // i 0..31
  const int n0 = (i / 8) * 256;
  const int rblk = xcd * 8 + (i % 8);                      // 0..63
  const int row0 = SH_OFF + rblk * 128;
  const int e = 8;

  extern __shared__ u16 sm[];

  const int tid = threadIdx.x;
  const int wvb = (tid >> 6) * 512;
  const int ra = tid >> 2;
  const int ca = (tid & 3) ^ ((ra >> 1) & 3);
  const u16* pA  = h + (size_t)(row0 + ra) * FP + ca * 8;
  const u16* pB0 = wd + ((size_t)e * DDIM + n0 + ra) * FP + ca * 8;
  const u16* pB1 = pB0 + (size_t)128 * FP;

  const int lane = tid & 63, wv = tid >> 6;
  const int wm = wv >> 2, wn = wv & 3;
  const int fr = lane & 15, kq = lane >> 4;
  const int kqs8 = (kq ^ ((fr >> 1) & 3)) * 8;

  f32x4 acc[16];
#pragma unroll
  for (int q = 0; q < 16; q++) acc[q] = (f32x4)(0.0f);

  async16(pA,        sm + 0     + wvb);
  async16(pB0,       sm + 4096  + wvb);
  async16(pB1,       sm + 8192  + wvb);
  async16(pA  + 32,  sm + 12288 + 0    + wvb);
  async16(pB0 + 32,  sm + 12288 + 4096 + wvb);
  async16(pB1 + 32,  sm + 12288 + 8192 + wvb);
  async16(pA  + 64,  sm + 24576 + 0    + wvb);
  async16(pB0 + 64,  sm + 24576 + 4096 + wvb);
  async16(pB1 + 64,  sm + 24576 + 8192 + wvb);
  asm volatile("s_waitcnt vmcnt(3)" ::: "memory");
  __builtin_amdgcn_s_barrier();

  bf16x8 aP[4], bP[4], aQ[4], bQ[4];
#pragma unroll
  for (int q = 0; q < 4; q++) {
    aP[q] = *(const bf16x8*)(sm + 0    + (wm * 64 + q * 16 + fr) * 32 + kqs8);
    bP[q] = *(const bf16x8*)(sm + 4096 + (wn * 64 + q * 16 + fr) * 32 + kqs8);
  }
  asm volatile("s_waitcnt lgkmcnt(0)" ::: "memory");
  __builtin_amdgcn_s_barrier();

  int bufC = 0, bufN = 12288, bufS = 24576;

  auto iter = [&](int T, bf16x8 (&AC)[4], bf16x8 (&BC)[4], bf16x8 (&AN)[4], bf16x8 (&BN)[4]) {
    if (T + 3 < 88) {
      async16(pA  + (T + 3) * 32, sm + bufC + 0    + wvb);
      async16(pB0 + (T + 3) * 32, sm + bufC + 4096 + wvb);
      async16(pB1 + (T + 3) * 32, sm + bufC + 8192 + wvb);
    }
    if (T + 1 < 88) {
#pragma unroll
      for (int q = 0; q < 4; q++) {
        AN[q] = *(const bf16x8*)(sm + bufN + 0    + (wm * 64 + q * 16 + fr) * 32 + kqs8);
        BN[q] = *(const bf16x8*)(sm + bufN + 4096 + (wn * 64 + q * 16 + fr) * 32 + kqs8);
      }
    }
    __builtin_amdgcn_sched_barrier(0);
    __builtin_amdgcn_s_setprio(1);
#pragma unroll
    for (int mi = 0; mi < 4; mi++)
#pragma unroll
      for (int ni = 0; ni < 4; ni++)
        acc[mi * 4 + ni] = __builtin_amdgcn_mfma_f32_16x16x32_bf16(AC[mi], BC[ni], acc[mi * 4 + ni], 0, 0, 0);
    __builtin_amdgcn_s_setprio(0);
    asm volatile("s_waitcnt lgkmcnt(0)" ::: "memory");
    if (T < 85) asm volatile("s_waitcnt vmcnt(3)" ::: "memory");
    else        asm volatile("s_waitcnt vmcnt(0)" ::: "memory");
    __builtin_amdgcn_s_barrier();
    int tmp = bufC; bufC = bufN; bufN = bufS; bufS = tmp;
  };

  for (int t = 0; t < 88; t += 2) {
    iter(t,     aP, bP, aQ, bQ);
    iter(t + 1, aQ, bQ, aP, bP);
  }

#pragma unroll
  for (int mi = 0; mi < 4; mi++)
#pragma unroll
    for (int r = 0; r < 4; r++) {
      int row = row0 + wm * 64 + mi * 16 + kq * 4 + r;
      int t = row - SH_OFF;
      int r1 = inv[2 * t], r2 = inv[2 * t + 1];
      float w1 = tw[r1], w2 = tw[r2];
      const u16* p1 = hd + (size_t)r1 * DDIM;
      const u16* p2 = hd + (size_t)r2 * DDIM;
      float* orow = out + (size_t)t * DDIM;
#pragma unroll
      for (int ni = 0; ni < 4; ni++) {
        int col = n0 + wn * 64 + ni * 16 + fr;
        orow[col] = acc[mi * 4 + ni][r] + w1 * b2f(p1[col]) + w2 * b2f(p2[col]);
      }
    }
}

// ---------------- host ----------------
extern "C" void kernel_launch(void* const* d_in, const int* in_sizes, int n_in,
                              void* d_out, int out_size, void* d_ws, size_t ws_size,
                              hipStream_t stream) {
  const float* x       = (const float*)d_in[0];
  const float* rw      = (const float*)d_in[1];
  const float* rb      = (const float*)d_in[2];
  const float* gate_w  = (const float*)d_in[3];
  const float* up_w    = (const float*)d_in[4];
  const float* down_w  = (const float*)d_in[5];
  const float* sh_gate = (const float*)d_in[6];
  const float* sh_up   = (const float*)d_in[7];
  const float* sh_down = (const float*)d_in[8];
  float* out = (float*)d_out;
  char* ws = (char*)d_ws;

  // ws layout (bytes)
  const size_t O_CTRL = 0;                       // 64 ints
  const size_t O_BMAP = 256;                     // int2[256]
  const size_t O_TID  = 2304;                    // int[T*2]
  const size_t O_TW   = O_TID + (size_t)TTOK * 2 * 4;
  const size_t O_TOK  = O_TW + (size_t)TTOK * 2 * 4;
  const size_t O_TKW  = O_TOK + (size_t)NA * 4;
  const size_t O_INV  = O_TKW + (size_t)NA * 4;  // int[T*2] inverse map
  const size_t O_ZEND = O_INV + (size_t)TTOK * 2 * 4;  // everything above zeroed
  const size_t O_XB   = (O_ZEND + 255) & ~(size_t)255;
  const size_t O_WG   = O_XB + (size_t)TTOK * DDIM * 2;
  const size_t O_WU   = O_WG + (size_t)9 * FP * DDIM * 2;
  const size_t O_WD   = O_WU + (size_t)9 * FP * DDIM * 2;
  const size_t O_H    = O_WD + (size_t)9 * DDIM * FP * 2;
  const size_t O_HD   = O_H + (size_t)NA * FP * 2;      // bf16 routed partials [SH_OFF][D]

  int*   ctrl = (int*)(ws + O_CTRL);
  int2*  bmap = (int2*)(ws + O_BMAP);
  int*   tid_ = (int*)(ws + O_TID);
  float* tw_  = (float*)(ws + O_TW);
  int*   tok  = (int*)(ws + O_TOK);
  float* tkw  = (float*)(ws + O_TKW);
  int*   inv  = (int*)(ws + O_INV);
  u16*   xb   = (u16*)(ws + O_XB);
  u16*   wg   = (u16*)(ws + O_WG);
  u16*   wu   = (u16*)(ws + O_WU);
  u16*   wd   = (u16*)(ws + O_WD);
  u16*   h    = (u16*)(ws + O_H);
  u16*   hd   = (u16*)(ws + O_HD);

  // opt-in to >64KiB dynamic LDS
  hipFuncSetAttribute((const void*)gemm_gateup, hipFuncAttributeMaxDynamicSharedMemorySize, 122880);
  hipFuncSetAttribute((const void*)gemm_down_r, hipFuncAttributeMaxDynamicSharedMemorySize, 73728);
  hipFuncSetAttribute((const void*)gemm_down_s, hipFuncAttributeMaxDynamicSharedMemorySize, 73728);

  hipMemsetAsync(ws, 0, O_ZEND, stream);

  cvt_x<<<dim3(TTOK * DDIM / 1024), 256, 0, stream>>>(x, xb);
  // gate/up: in [D][F] -> out [FP][D]
  transpose_cvt<<<dim3(16, 44, 9), 256, 0, stream>>>(gate_w, sh_gate, wg, DDIM, FDIM, FP, DDIM);
  transpose_cvt<<<dim3(16, 44, 9), 256, 0, stream>>>(up_w, sh_up, wu, DDIM, FDIM, FP, DDIM);
  // down: in [F][D] -> out [D][FP]
  transpose_cvt<<<dim3(44, 16, 9), 256, 0, stream>>>(down_w, sh_down, wd, FDIM, DDIM, DDIM, FP);

  router_kernel<<<dim3(TTOK / 4), 256, 0, stream>>>(x, rw, rb, tid_, tw_, ctrl);
  build_kernel<<<dim3(1), 64, 0, stream>>>(ctrl, bmap);
  fill_kernel<<<dim3(TTOK / 256), 256, 0, stream>>>(tid_, tw_, ctrl, tok, tkw, inv);

  gemm_gateup<<<dim3(8 * 275), 512, 122880, stream>>>(xb, wg, wu, ctrl, bmap, tok, h);
  gemm_down_r<<<dim3(8 * 68), 512, 73728, stream>>>(h, wd, ctrl, bmap, hd);
  gemm_down_s<<<dim3(8 * 32), 512, 73728, stream>>>(h, wd, hd, inv, tkw, out);
}